// Round 11
// baseline (686.016 us; speedup 1.0000x reference)
//
#include <hip/hip_runtime.h>

// Problem constants (match reference)
#define D_   41
#define H_   159
#define W_   159
#define MD   20
#define MH   79
#define MW   79
#define CIN  32
#define COUT 64
#define BATCH 2

#define NTAP 27
// Packed weight table: [tap][j4][co][k], u32 = bf16 ci-pair; lane co reads 16B
// contiguous -> coalesced. 27*16*64*4 = 110,592 B.
// mid: reads it from GLOBAL (L2-resident, replicated per XCD) -> no LDS -> no
// 1-block/CU occupancy cap -> 32 waves/CU. (Round 6's no-LDS attempt failed
// only because launch_bounds(,8) forced VGPR=32 + spill; plain bounds give 64.)
// out: keeps the LDS copy (acc[32] makes it register-tight already).
#define WLDS (NTAP * 16 * 64)

#define BLK   1024
#define WPB   (BLK / 64)

typedef unsigned int u32;

static __device__ __forceinline__ u32 bf16_rn(float x) {
    u32 u = __float_as_uint(x);
    return (u + 0x7fffu + ((u >> 16) & 1u)) >> 16;   // round-to-nearest-even
}
static __device__ __forceinline__ float bf_lo(u32 p) { return __uint_as_float(p << 16); }
static __device__ __forceinline__ float bf_hi(u32 p) { return __uint_as_float(p & 0xffff0000u); }

// Pack w (fp32 [tap][ci][co]) -> [tap][j4][co][k] bf16-pairs (pair j=4*j4+k = ci 2j,2j+1).
__global__ void pack_kernel(const float* __restrict__ w1, const float* __restrict__ w2,
                            u32* __restrict__ w1p, u32* __restrict__ w2p) {
    int i = blockIdx.x * 256 + threadIdx.x;
    if (i >= WLDS) return;
    int k  = i & 3;
    int co = (i >> 2) & 63;
    int j4 = (i >> 8) & 3;
    int t  = i >> 10;
    int j  = j4 * 4 + k;
    int s0 = (t * 32 + 2 * j) * 64 + co;
    int s1 = (t * 32 + 2 * j + 1) * 64 + co;
    w1p[i] = bf16_rn(w1[s0]) | (bf16_rn(w1[s1]) << 16);
    w2p[i] = bf16_rn(w2[s0]) | (bf16_rn(w2[s1]) << 16);
}

// Scatter point index into dense idx grid (-1 = empty).
__global__ void scatter_idx_kernel(const int* __restrict__ coors,
                                   int* __restrict__ idx, int n) {
    int i = blockIdx.x * blockDim.x + threadIdx.x;
    if (i >= n) return;
    int4 c = ((const int4*)coors)[i];
    idx[((c.x * D_ + c.y) * H_ + c.z) * W_ + c.w] = i;
}

// Weight read from an arbitrary base (LDS or global): 4 x 16B per lane,
// 1KB contiguous per wave per quad -> coalesced / conflict-free.
#define LOADW(dst, base, t)                                        \
    {                                                              \
        const uint4* wq = (const uint4*)(base) + (t) * 256 + lane; \
        uint4 q0 = wq[0], q1 = wq[64], q2 = wq[128], q3 = wq[192]; \
        dst[0] = q0.x;  dst[1] = q0.y;  dst[2] = q0.z;  dst[3] = q0.w;   \
        dst[4] = q1.x;  dst[5] = q1.y;  dst[6] = q1.z;  dst[7] = q1.w;   \
        dst[8] = q2.x;  dst[9] = q2.y;  dst[10] = q2.z; dst[11] = q2.w;  \
        dst[12] = q3.x; dst[13] = q3.y; dst[14] = q3.z; dst[15] = q3.w;  \
    }

// mid: one wave per voxel PAIR per iteration; probes prefetched; two event
// streams interleaved; weights from L2 (no LDS -> 32 waves/CU for latency
// hiding of the ~500cy random feat-row loads).
__global__ __launch_bounds__(BLK) void mid_kernel(const float* __restrict__ feat,
                                                  const int* __restrict__ idx,
                                                  const u32* __restrict__ w1p,
                                                  float* __restrict__ mid) {
    const int NV = BATCH * MD * MH * MW;
    int lane = threadIdx.x & 63;
    int wid  = threadIdx.x >> 6;
    int nw   = gridDim.x * WPB;
    int gw   = blockIdx.x * WPB + wid;
    int per  = (NV + nw - 1) / nw;
    int v0   = gw * per;
    int v1   = v0 + per; if (v1 > NV) v1 = NV;

    int l  = lane < NTAP ? lane : NTAP - 1;
    int kz = l / 9, kr = l % 9, ky = kr / 3, kx = kr % 3;

    auto probe = [&](int v) -> int {
        if (v >= v1 || lane >= NTAP) return -1;
        int xo = v % MW; int t0 = v / MW;
        int yo = t0 % MH; t0 /= MH;
        int zo = t0 % MD; int b = t0 / MD;
        return idx[((b * D_ + 2 * zo + kz) * H_ + 2 * yo + ky) * W_ + 2 * xo + kx];
    };

    int pA = probe(v0), pB = probe(v0 + 1);
    for (int v = v0; v < v1; v += 2) {
        int cA = pA, cB = pB;
        pA = probe(v + 2);            // prefetch next pair's probes
        pB = probe(v + 3);
        unsigned long long mA = __ballot(cA >= 0);
        unsigned long long mB = __ballot(cB >= 0);

        float a0 = 0.f, a1 = 0.f, b0 = 0.f, b1 = 0.f;
        while (mA | mB) {
            bool hA = mA != 0, hB = mB != 0;   // wave-uniform
            float4 fav[8], fbv[8];
            u32 wav[16], wbv[16];
            if (hA) {
                int t = (int)__builtin_ctzll(mA); mA &= mA - 1;
                int pp = __shfl(cA, t);
                const float4* f4 = (const float4*)(feat + (size_t)pp * CIN);
                #pragma unroll
                for (int q = 0; q < 8; ++q) fav[q] = f4[q];
                LOADW(wav, w1p, t)
            }
            if (hB) {
                int t = (int)__builtin_ctzll(mB); mB &= mB - 1;
                int pp = __shfl(cB, t);
                const float4* f4 = (const float4*)(feat + (size_t)pp * CIN);
                #pragma unroll
                for (int q = 0; q < 8; ++q) fbv[q] = f4[q];
                LOADW(wbv, w1p, t)
            }
            if (hA) {
                #pragma unroll
                for (int q = 0; q < 8; ++q) {
                    a0 = fmaf(fav[q].x, bf_lo(wav[2 * q + 0]), a0);
                    a1 = fmaf(fav[q].y, bf_hi(wav[2 * q + 0]), a1);
                    a0 = fmaf(fav[q].z, bf_lo(wav[2 * q + 1]), a0);
                    a1 = fmaf(fav[q].w, bf_hi(wav[2 * q + 1]), a1);
                }
            }
            if (hB) {
                #pragma unroll
                for (int q = 0; q < 8; ++q) {
                    b0 = fmaf(fbv[q].x, bf_lo(wbv[2 * q + 0]), b0);
                    b1 = fmaf(fbv[q].y, bf_hi(wbv[2 * q + 0]), b1);
                    b0 = fmaf(fbv[q].z, bf_lo(wbv[2 * q + 1]), b0);
                    b1 = fmaf(fbv[q].w, bf_hi(wbv[2 * q + 1]), b1);
                }
            }
        }
        mid[(size_t)v * COUT + lane] = a0 + a1;
        if (v + 1 < v1) mid[(size_t)(v + 1) * COUT + lane] = b0 + b1;
    }
}

// Statically-unrolled butterfly reduce-scatter step (no dynamic indexing -> no spill).
#define BSTEP(MK, HALF)                                            \
    {                                                              \
        bool up = (lane & MK) != 0;                                \
        _Pragma("unroll")                                          \
        for (int k = 0; k < HALF; ++k) {                           \
            float send = up ? acc[k] : acc[k + HALF];              \
            float keep = up ? acc[k + HALF] : acc[k];              \
            acc[k] = keep + __shfl_xor(send, MK, 64);              \
        }                                                          \
    }

// out: one wave per point; coors prefetched; events in PAIRS; w2 in LDS (b128).
// Writes a COMPACT [n][32] row per point (coalesced 128B); expand_kernel
// materializes the dense output with full-line coalesced stores.
__global__ __launch_bounds__(BLK) void out_kernel(const int* __restrict__ coors,
                                                  const float* __restrict__ mid,
                                                  const u32* __restrict__ w2p,
                                                  float* __restrict__ compact, int n) {
    __shared__ u32 lw[WLDS];
    for (int i = threadIdx.x; i < WLDS; i += BLK) lw[i] = w2p[i];
    __syncthreads();

    int lane = threadIdx.x & 63;
    int wid  = threadIdx.x >> 6;
    int nw   = gridDim.x * WPB;
    int gw   = blockIdx.x * WPB + wid;
    int per  = (n + nw - 1) / nw;
    int i0   = gw * per;
    int i1   = i0 + per; if (i1 > n) i1 = n;

    int l  = lane < NTAP ? lane : NTAP - 1;
    int kz = l / 9, kr = l % 9, ky = kr / 3, kx = kr % 3;

    const int4* cvec = (const int4*)coors;
    int4 nc = make_int4(0, 0, 0, 0);
    if (i0 < i1) nc = cvec[i0];

    for (int i = i0; i < i1; ++i) {
        int4 c = nc;
        if (i + 1 < i1) nc = cvec[i + 1];   // prefetch next point
        int b = c.x, z = c.y, y = c.z, x = c.w;

        int zr = z - kz, yr = y - ky, xr = x - kx;
        bool ok = (lane < NTAP) &&
                  zr >= 0 && !(zr & 1) && (zr >> 1) < MD &&
                  yr >= 0 && !(yr & 1) && (yr >> 1) < MH &&
                  xr >= 0 && !(xr & 1) && (xr >> 1) < MW;
        int vv = ok ? ((b * MD + (zr >> 1)) * MH + (yr >> 1)) * MW + (xr >> 1) : -1;
        unsigned long long m = __ballot(ok);

        float acc[CIN];
        #pragma unroll
        for (int ci = 0; ci < CIN; ++ci) acc[ci] = 0.f;

        while (m) {
            int t0 = (int)__builtin_ctzll(m); m &= m - 1;
            bool h1 = (m != 0);               // wave-uniform
            int t1 = 0;
            if (h1) { t1 = (int)__builtin_ctzll(m); m &= m - 1; }

            int ve0 = __shfl(vv, t0);
            float mr0 = mid[(size_t)ve0 * COUT + lane];
            u32 wv0[16];
            LOADW(wv0, lw, t0)

            float mr1 = 0.f; u32 wv1[16];
            if (h1) {
                int ve1 = __shfl(vv, t1);
                mr1 = mid[(size_t)ve1 * COUT + lane];
                LOADW(wv1, lw, t1)
            }

            #pragma unroll
            for (int j = 0; j < 16; ++j) {
                acc[2 * j + 0] = fmaf(mr0, bf_lo(wv0[j]), acc[2 * j + 0]);
                acc[2 * j + 1] = fmaf(mr0, bf_hi(wv0[j]), acc[2 * j + 1]);
            }
            if (h1) {
                #pragma unroll
                for (int j = 0; j < 16; ++j) {
                    acc[2 * j + 0] = fmaf(mr1, bf_lo(wv1[j]), acc[2 * j + 0]);
                    acc[2 * j + 1] = fmaf(mr1, bf_hi(wv1[j]), acc[2 * j + 1]);
                }
            }
        }

        // Reduce-scatter 32 ci over 64 lanes (co): 5 static butterfly steps.
        BSTEP(32, 16)
        BSTEP(16, 8)
        BSTEP(8, 4)
        BSTEP(4, 2)
        BSTEP(2, 1)
        float s = acc[0] + __shfl_xor(acc[0], 1, 64);
        if (!(lane & 1))
            compact[(size_t)i * CIN + (lane >> 1)] = s;   // 128B/point, coalesced
    }
}

// expand: dense sweep of the output grid. Per voxel g (layout-identical to
// idx): read idx[g]; load that point's compact row (or zeros); write all 32
// ci planes with coalesced stores. Every output line is written exactly once,
// full-width -> pure streaming-write roofline (~265MB write + ~27MB read).
__global__ __launch_bounds__(256) void expand_kernel(const int* __restrict__ idx,
                                                     const float* __restrict__ compact,
                                                     float* __restrict__ out) {
    const int HW    = H_ * W_;
    const int PLANE = D_ * HW;            // 1,036,521 elements per (b,ci) plane
    const int NVOX  = BATCH * PLANE;      // 2,073,042
    int g = blockIdx.x * 256 + threadIdx.x;
    if (g >= NVOX) return;

    int p   = idx[g];
    int b   = g / PLANE;
    int rem = g - b * PLANE;              // z*HW + y*W + x

    float r[CIN];
    if (p >= 0) {
        const float4* row = (const float4*)(compact + (size_t)p * CIN);
        #pragma unroll
        for (int q = 0; q < 8; ++q) {
            float4 v = row[q];
            r[4 * q + 0] = v.x; r[4 * q + 1] = v.y;
            r[4 * q + 2] = v.z; r[4 * q + 3] = v.w;
        }
    } else {
        #pragma unroll
        for (int q = 0; q < CIN; ++q) r[q] = 0.f;
    }

    float* o = out + (size_t)b * ((size_t)CIN * PLANE) + rem;
    #pragma unroll
    for (int ci = 0; ci < CIN; ++ci)
        __builtin_nontemporal_store(r[ci], o + (size_t)ci * PLANE);
}

extern "C" void kernel_launch(void* const* d_in, const int* in_sizes, int n_in,
                              void* d_out, int out_size, void* d_ws, size_t ws_size,
                              hipStream_t stream) {
    const float* feat  = (const float*)d_in[0];
    const int*   coors = (const int*)d_in[1];
    const float* w1    = (const float*)d_in[3];
    const float* w2    = (const float*)d_in[4];
    float*       out   = (float*)d_out;

    int n = in_sizes[0] / CIN;   // 150000 points total

    // Workspace: [idx 8.3MB][mid 63.9MB][w1p+w2p 221KB][compact 19.2MB]
    int*   idx      = (int*)d_ws;
    size_t idxBytes = (size_t)BATCH * D_ * H_ * W_ * sizeof(int);
    size_t midOff   = (idxBytes + 255) & ~(size_t)255;
    float* mid      = (float*)((char*)d_ws + midOff);
    size_t wOff     = midOff + (size_t)BATCH * MD * MH * MW * COUT * sizeof(float);
    wOff            = (wOff + 255) & ~(size_t)255;
    u32*   w1p      = (u32*)((char*)d_ws + wOff);
    u32*   w2p      = w1p + WLDS;
    float* compact  = (float*)(w2p + WLDS);   // 16B-aligned

    (void)hipMemsetAsync(idx, 0xFF, idxBytes, stream);   // idx = -1
    // No dense-output memset: expand_kernel writes every output element
    // exactly once (zeros included), full-line coalesced.

    pack_kernel<<<(WLDS + 255) / 256, 256, 0, stream>>>(w1, w2, w1p, w2p);
    scatter_idx_kernel<<<(n + 255) / 256, 256, 0, stream>>>(coors, idx, n);

    mid_kernel<<<512, BLK, 0, stream>>>(feat, idx, w1p, mid);   // 2 blocks/CU
    out_kernel<<<256, BLK, 0, stream>>>(coors, mid, w2p, compact, n);

    const int NVOX = BATCH * D_ * H_ * W_;
    expand_kernel<<<(NVOX + 255) / 256, 256, 0, stream>>>(idx, compact, out);
}

// Round 13
// 561.163 us; speedup vs baseline: 1.2225x; 1.2225x over previous
//
#include <hip/hip_runtime.h>

// Problem constants (match reference)
#define D_   41
#define H_   159
#define W_   159
#define MD   20
#define MH   79
#define MW   79
#define CIN  32
#define COUT 64
#define BATCH 2

#define NTAP 27
// LDS weight table: [tap][j4][co][k], u32 = f16 ci-pair. Lane co reads 16B
// contiguous at ((t*4+j4)*64+co)*16 -> conflict-free ds_read_b128.
// 27*16*64*4 = 110,592 B. LDS staging is mandatory: round-11 proved moving
// LOADW to L2 puts ~200cy on the critical path (173->236us).
#define WLDS (NTAP * 16 * 64)

#define BLK   1024
#define WPB   (BLK / 64)

typedef unsigned int u32;
typedef unsigned short u16;
typedef _Float16 f16;
typedef f16 f16x2 __attribute__((ext_vector_type(2)));

// Pack two floats into one u32 of f16 pair (RTNE via scalar casts).
static __device__ __forceinline__ u32 f16pair(float a, float b) {
    f16x2 h = { (f16)a, (f16)b };
    return __builtin_bit_cast(u32, h);
}
// f32 accumulate of an f16-pair dot product: c += a.lo*b.lo + a.hi*b.hi.
static __device__ __forceinline__ float dot2(u32 a, u32 b, float c) {
    return __builtin_amdgcn_fdot2(__builtin_bit_cast(f16x2, a),
                                  __builtin_bit_cast(f16x2, b), c, false);
}

// Pack w (fp32 [tap][ci][co]) -> [tap][j4][co][k] f16-pairs (pair j=4*j4+k = ci 2j,2j+1).
__global__ void pack_kernel(const float* __restrict__ w1, const float* __restrict__ w2,
                            u32* __restrict__ w1p, u32* __restrict__ w2p) {
    int i = blockIdx.x * 256 + threadIdx.x;
    if (i >= WLDS) return;
    int k  = i & 3;
    int co = (i >> 2) & 63;
    int j4 = (i >> 8) & 3;
    int t  = i >> 10;
    int j  = j4 * 4 + k;
    int s0 = (t * 32 + 2 * j) * 64 + co;
    int s1 = (t * 32 + 2 * j + 1) * 64 + co;
    w1p[i] = f16pair(w1[s0], w1[s1]);
    w2p[i] = f16pair(w2[s0], w2[s1]);
}

// Pack feat rows (fp32 [n][32]) -> f16 pairs [n][16] u32 (halves gather bytes).
__global__ void featpack_kernel(const float* __restrict__ feat,
                                u32* __restrict__ feat_h, int n16) {
    int i = blockIdx.x * 256 + threadIdx.x;
    if (i >= n16) return;
    int p = i >> 4, j = i & 15;
    feat_h[i] = f16pair(feat[p * CIN + 2 * j], feat[p * CIN + 2 * j + 1]);
}

// Scatter point index into dense idx grid (-1 = empty).
__global__ void scatter_idx_kernel(const int* __restrict__ coors,
                                   int* __restrict__ idx, int n) {
    int i = blockIdx.x * blockDim.x + threadIdx.x;
    if (i >= n) return;
    int4 c = ((const int4*)coors)[i];
    idx[((c.x * D_ + c.y) * H_ + c.z) * W_ + c.w] = i;
}

// Load one event's 16 weight pairs via 4 conflict-free ds_read_b128.
#define LOADW(dst, base, t)                                        \
    {                                                              \
        const uint4* wq = (const uint4*)(base) + (t) * 256 + lane; \
        uint4 q0 = wq[0], q1 = wq[64], q2 = wq[128], q3 = wq[192]; \
        dst[0] = q0.x;  dst[1] = q0.y;  dst[2] = q0.z;  dst[3] = q0.w;   \
        dst[4] = q1.x;  dst[5] = q1.y;  dst[6] = q1.z;  dst[7] = q1.w;   \
        dst[8] = q2.x;  dst[9] = q2.y;  dst[10] = q2.z; dst[11] = q2.w;  \
        dst[12] = q3.x; dst[13] = q3.y; dst[14] = q3.z; dst[15] = q3.w;  \
    }

// mid: one wave per voxel PAIR; probes prefetched; two event streams; w1 in
// LDS; feat/weights as f16 pairs -> 16 v_dot2_f32_f16 per event (was 64
// FMA+bit-ops) and half the feat gather bytes. Output mid stored as f16.
__global__ __launch_bounds__(BLK) void mid_kernel(const u32* __restrict__ feat_h,
                                                  const int* __restrict__ idx,
                                                  const u32* __restrict__ w1p,
                                                  u16* __restrict__ mid_h) {
    __shared__ u32 lw[WLDS];
    for (int i = threadIdx.x; i < WLDS; i += BLK) lw[i] = w1p[i];
    __syncthreads();

    const int NV = BATCH * MD * MH * MW;
    int lane = threadIdx.x & 63;
    int wid  = threadIdx.x >> 6;
    int nw   = gridDim.x * WPB;
    int gw   = blockIdx.x * WPB + wid;
    int per  = (NV + nw - 1) / nw;
    int v0   = gw * per;
    int v1   = v0 + per; if (v1 > NV) v1 = NV;

    int l  = lane < NTAP ? lane : NTAP - 1;
    int kz = l / 9, kr = l % 9, ky = kr / 3, kx = kr % 3;

    auto probe = [&](int v) -> int {
        if (v >= v1 || lane >= NTAP) return -1;
        int xo = v % MW; int t0 = v / MW;
        int yo = t0 % MH; t0 /= MH;
        int zo = t0 % MD; int b = t0 / MD;
        return idx[((b * D_ + 2 * zo + kz) * H_ + 2 * yo + ky) * W_ + 2 * xo + kx];
    };

    int pA = probe(v0), pB = probe(v0 + 1);
    for (int v = v0; v < v1; v += 2) {
        int cA = pA, cB = pB;
        pA = probe(v + 2);            // prefetch next pair's probes
        pB = probe(v + 3);
        unsigned long long mA = __ballot(cA >= 0);
        unsigned long long mB = __ballot(cB >= 0);

        float a0 = 0.f, a1 = 0.f, b0 = 0.f, b1 = 0.f;
        while (mA | mB) {
            bool hA = mA != 0, hB = mB != 0;   // wave-uniform
            uint4 fa0, fa1, fa2, fa3, fb0, fb1, fb2, fb3;
            u32 wav[16], wbv[16];
            if (hA) {
                int t = (int)__builtin_ctzll(mA); mA &= mA - 1;
                int pp = __shfl(cA, t);
                const uint4* f4 = (const uint4*)(feat_h + (size_t)pp * 16);
                fa0 = f4[0]; fa1 = f4[1]; fa2 = f4[2]; fa3 = f4[3];
                LOADW(wav, lw, t)
            }
            if (hB) {
                int t = (int)__builtin_ctzll(mB); mB &= mB - 1;
                int pp = __shfl(cB, t);
                const uint4* f4 = (const uint4*)(feat_h + (size_t)pp * 16);
                fb0 = f4[0]; fb1 = f4[1]; fb2 = f4[2]; fb3 = f4[3];
                LOADW(wbv, lw, t)
            }
            if (hA) {
                a0 = dot2(fa0.x, wav[0],  a0);  a1 = dot2(fa0.y, wav[1],  a1);
                a0 = dot2(fa0.z, wav[2],  a0);  a1 = dot2(fa0.w, wav[3],  a1);
                a0 = dot2(fa1.x, wav[4],  a0);  a1 = dot2(fa1.y, wav[5],  a1);
                a0 = dot2(fa1.z, wav[6],  a0);  a1 = dot2(fa1.w, wav[7],  a1);
                a0 = dot2(fa2.x, wav[8],  a0);  a1 = dot2(fa2.y, wav[9],  a1);
                a0 = dot2(fa2.z, wav[10], a0);  a1 = dot2(fa2.w, wav[11], a1);
                a0 = dot2(fa3.x, wav[12], a0);  a1 = dot2(fa3.y, wav[13], a1);
                a0 = dot2(fa3.z, wav[14], a0);  a1 = dot2(fa3.w, wav[15], a1);
            }
            if (hB) {
                b0 = dot2(fb0.x, wbv[0],  b0);  b1 = dot2(fb0.y, wbv[1],  b1);
                b0 = dot2(fb0.z, wbv[2],  b0);  b1 = dot2(fb0.w, wbv[3],  b1);
                b0 = dot2(fb1.x, wbv[4],  b0);  b1 = dot2(fb1.y, wbv[5],  b1);
                b0 = dot2(fb1.z, wbv[6],  b0);  b1 = dot2(fb1.w, wbv[7],  b1);
                b0 = dot2(fb2.x, wbv[8],  b0);  b1 = dot2(fb2.y, wbv[9],  b1);
                b0 = dot2(fb2.z, wbv[10], b0);  b1 = dot2(fb2.w, wbv[11], b1);
                b0 = dot2(fb3.x, wbv[12], b0);  b1 = dot2(fb3.y, wbv[13], b1);
                b0 = dot2(fb3.z, wbv[14], b0);  b1 = dot2(fb3.w, wbv[15], b1);
            }
        }
        {
            f16 hv = (f16)(a0 + a1);
            mid_h[(size_t)v * COUT + lane] = __builtin_bit_cast(u16, hv);
        }
        if (v + 1 < v1) {
            f16 hv = (f16)(b0 + b1);
            mid_h[(size_t)(v + 1) * COUT + lane] = __builtin_bit_cast(u16, hv);
        }
    }
}

// Statically-unrolled butterfly reduce-scatter step (no dynamic indexing -> no spill).
#define BSTEP(MK, HALF)                                            \
    {                                                              \
        bool up = (lane & MK) != 0;                                \
        _Pragma("unroll")                                          \
        for (int k = 0; k < HALF; ++k) {                           \
            float send = up ? acc[k] : acc[k + HALF];              \
            float keep = up ? acc[k + HALF] : acc[k];              \
            acc[k] = keep + __shfl_xor(send, MK, 64);              \
        }                                                          \
    }

// out: one wave per point; events in PAIRS fused via v_perm + dot2:
// acc[2j]   += dot2(pack(mr0,mr1), pack(w0_lo, w1_lo))
// acc[2j+1] += dot2(pack(mr0,mr1), pack(w0_hi, w1_hi))
// mr1=0 kills the second term when the pair is odd (w from tap 0, finite).
// Writes a COMPACT [n][32] f32 row; expand_kernel densifies.
__global__ __launch_bounds__(BLK) void out_kernel(const int* __restrict__ coors,
                                                  const u16* __restrict__ mid_h,
                                                  const u32* __restrict__ w2p,
                                                  float* __restrict__ compact, int n) {
    __shared__ u32 lw[WLDS];
    for (int i = threadIdx.x; i < WLDS; i += BLK) lw[i] = w2p[i];
    __syncthreads();

    int lane = threadIdx.x & 63;
    int wid  = threadIdx.x >> 6;
    int nw   = gridDim.x * WPB;
    int gw   = blockIdx.x * WPB + wid;
    int per  = (n + nw - 1) / nw;
    int i0   = gw * per;
    int i1   = i0 + per; if (i1 > n) i1 = n;

    int l  = lane < NTAP ? lane : NTAP - 1;
    int kz = l / 9, kr = l % 9, ky = kr / 3, kx = kr % 3;

    const int4* cvec = (const int4*)coors;
    int4 nc = make_int4(0, 0, 0, 0);
    if (i0 < i1) nc = cvec[i0];

    for (int i = i0; i < i1; ++i) {
        int4 c = nc;
        if (i + 1 < i1) nc = cvec[i + 1];   // prefetch next point
        int b = c.x, z = c.y, y = c.z, x = c.w;

        int zr = z - kz, yr = y - ky, xr = x - kx;
        bool ok = (lane < NTAP) &&
                  zr >= 0 && !(zr & 1) && (zr >> 1) < MD &&
                  yr >= 0 && !(yr & 1) && (yr >> 1) < MH &&
                  xr >= 0 && !(xr & 1) && (xr >> 1) < MW;
        int vv = ok ? ((b * MD + (zr >> 1)) * MH + (yr >> 1)) * MW + (xr >> 1) : -1;
        unsigned long long m = __ballot(ok);

        float acc[CIN];
        #pragma unroll
        for (int ci = 0; ci < CIN; ++ci) acc[ci] = 0.f;

        while (m) {
            int t0 = (int)__builtin_ctzll(m); m &= m - 1;
            bool h1 = (m != 0);               // wave-uniform
            int t1 = 0;
            if (h1) { t1 = (int)__builtin_ctzll(m); m &= m - 1; }

            int ve0 = __shfl(vv, t0);
            u32 mr0 = mid_h[(size_t)ve0 * COUT + lane];
            u32 mr1 = 0;
            if (h1) {
                int ve1 = __shfl(vv, t1);
                mr1 = mid_h[(size_t)ve1 * COUT + lane];
            }
            u32 mrp = mr0 | (mr1 << 16);

            u32 wv0[16], wv1[16];
            LOADW(wv0, lw, t0)
            LOADW(wv1, lw, t1)   // t1=0 when odd: finite weights x mr1=0 = 0

            #pragma unroll
            for (int j = 0; j < 16; ++j) {
                u32 wlo = __builtin_amdgcn_perm(wv1[j], wv0[j], 0x05040100u);
                u32 whi = __builtin_amdgcn_perm(wv1[j], wv0[j], 0x07060302u);
                acc[2 * j + 0] = dot2(mrp, wlo, acc[2 * j + 0]);
                acc[2 * j + 1] = dot2(mrp, whi, acc[2 * j + 1]);
            }
        }

        // Reduce-scatter 32 ci over 64 lanes (co): 5 static butterfly steps.
        BSTEP(32, 16)
        BSTEP(16, 8)
        BSTEP(8, 4)
        BSTEP(4, 2)
        BSTEP(2, 1)
        float s = acc[0] + __shfl_xor(acc[0], 1, 64);
        if (!(lane & 1))
            compact[(size_t)i * CIN + (lane >> 1)] = s;   // 128B/point, coalesced
    }
}

// expand: dense sweep of the output grid. Per voxel g (layout-identical to
// idx): read idx[g]; load that point's compact row (or zeros); write all 32
// ci planes coalesced. Every output line written exactly once, full-width.
__global__ __launch_bounds__(256) void expand_kernel(const int* __restrict__ idx,
                                                     const float* __restrict__ compact,
                                                     float* __restrict__ out) {
    const int HW    = H_ * W_;
    const int PLANE = D_ * HW;            // 1,036,521 elements per (b,ci) plane
    const int NVOX  = BATCH * PLANE;      // 2,073,042
    int g = blockIdx.x * 256 + threadIdx.x;
    if (g >= NVOX) return;

    int p   = idx[g];
    int b   = g / PLANE;
    int rem = g - b * PLANE;              // z*HW + y*W + x

    float r[CIN];
    if (p >= 0) {
        const float4* row = (const float4*)(compact + (size_t)p * CIN);
        #pragma unroll
        for (int q = 0; q < 8; ++q) {
            float4 v = row[q];
            r[4 * q + 0] = v.x; r[4 * q + 1] = v.y;
            r[4 * q + 2] = v.z; r[4 * q + 3] = v.w;
        }
    } else {
        #pragma unroll
        for (int q = 0; q < CIN; ++q) r[q] = 0.f;
    }

    float* o = out + (size_t)b * ((size_t)CIN * PLANE) + rem;
    #pragma unroll
    for (int ci = 0; ci < CIN; ++ci)
        __builtin_nontemporal_store(r[ci], o + (size_t)ci * PLANE);
}

extern "C" void kernel_launch(void* const* d_in, const int* in_sizes, int n_in,
                              void* d_out, int out_size, void* d_ws, size_t ws_size,
                              hipStream_t stream) {
    const float* feat  = (const float*)d_in[0];
    const int*   coors = (const int*)d_in[1];
    const float* w1    = (const float*)d_in[3];
    const float* w2    = (const float*)d_in[4];
    float*       out   = (float*)d_out;

    int n = in_sizes[0] / CIN;   // 150000 points total

    // Workspace:
    // [idx 8.3MB][mid_h 32MB][w1p+w2p 221KB][compact 19.2MB][feat_h 9.6MB]
    int*   idx      = (int*)d_ws;
    size_t idxBytes = (size_t)BATCH * D_ * H_ * W_ * sizeof(int);
    size_t midOff   = (idxBytes + 255) & ~(size_t)255;
    u16*   mid_h    = (u16*)((char*)d_ws + midOff);
    size_t wOff     = midOff + (size_t)BATCH * MD * MH * MW * COUT * sizeof(u16);
    wOff            = (wOff + 255) & ~(size_t)255;
    u32*   w1p      = (u32*)((char*)d_ws + wOff);
    u32*   w2p      = w1p + WLDS;
    float* compact  = (float*)(w2p + WLDS);            // 256-aligned
    u32*   feat_h   = (u32*)(compact + (size_t)n * CIN);

    (void)hipMemsetAsync(idx, 0xFF, idxBytes, stream);   // idx = -1
    // No dense-output memset: expand_kernel writes every output element.

    pack_kernel<<<(WLDS + 255) / 256, 256, 0, stream>>>(w1, w2, w1p, w2p);
    featpack_kernel<<<(n * 16 + 255) / 256, 256, 0, stream>>>(feat, feat_h, n * 16);
    scatter_idx_kernel<<<(n + 255) / 256, 256, 0, stream>>>(coors, idx, n);

    mid_kernel<<<256, BLK, 0, stream>>>(feat_h, idx, w1p, mid_h);
    out_kernel<<<256, BLK, 0, stream>>>(coors, mid_h, w2p, compact, n);

    const int NVOX = BATCH * D_ * H_ * W_;
    expand_kernel<<<(NVOX + 255) / 256, 256, 0, stream>>>(idx, compact, out);
}